// Round 1
// baseline (545.680 us; speedup 1.0000x reference)
//
#include <hip/hip_runtime.h>
#include <stdint.h>

#define D_MODEL 2048
#define SEQ     2048
#define BATCH   2
#define NH      16
#define HD      128
#define M_TOT   (BATCH*SEQ)          // 4096
#define NELEM_W (D_MODEL*D_MODEL)    // 4194304

typedef float f32x4 __attribute__((ext_vector_type(4)));
typedef short bf16x8 __attribute__((ext_vector_type(8)));

__device__ __forceinline__ unsigned short f2bf(float f) {
  union { float f; uint32_t u; } v; v.f = f;
  uint32_t r = v.u + 0x7FFFu + ((v.u >> 16) & 1u);
  return (unsigned short)(r >> 16);
}

__device__ __forceinline__ void gload_lds16(const unsigned short* g, unsigned short* l) {
  __builtin_amdgcn_global_load_lds(
      (const __attribute__((address_space(1))) unsigned int*)g,
      (__attribute__((address_space(3))) unsigned int*)l, 16, 0, 0);
}

// ---------------- scale reduction: s = max(mean|w|, 1e-5) ----------------
__global__ __launch_bounds__(256) void reduce1(const float* w0, const float* w1,
                                               const float* w2, const float* w3,
                                               float* partials) {
  const int wi = blockIdx.y;
  const float* w = (wi == 0) ? w0 : (wi == 1) ? w1 : (wi == 2) ? w2 : w3;
  const float4* w4 = (const float4*)w;
  const int t = threadIdx.x, bx = blockIdx.x;
  float s = 0.f;
  #pragma unroll
  for (int i = 0; i < 16; ++i) {
    float4 v = w4[(size_t)bx * 4096 + i * 256 + t];
    s += fabsf(v.x) + fabsf(v.y) + fabsf(v.z) + fabsf(v.w);
  }
  #pragma unroll
  for (int off = 32; off; off >>= 1) s += __shfl_down(s, off);
  __shared__ float sm[4];
  if ((t & 63) == 0) sm[t >> 6] = s;
  __syncthreads();
  if (t == 0) partials[wi * 256 + bx] = sm[0] + sm[1] + sm[2] + sm[3];
}

__global__ __launch_bounds__(256) void reduce2(const float* partials, float* scales) {
  const int wi = blockIdx.x, t = threadIdx.x;
  float s = partials[wi * 256 + t];
  #pragma unroll
  for (int off = 32; off; off >>= 1) s += __shfl_down(s, off);
  __shared__ float sm[4];
  if ((t & 63) == 0) sm[t >> 6] = s;
  __syncthreads();
  if (t == 0) scales[wi] = fmaxf((sm[0] + sm[1] + sm[2] + sm[3]) * (1.f / 4194304.f), 1e-5f);
}

// ---------------- x -> bf16 ----------------
__global__ __launch_bounds__(256) void cvt_x(const float* x, unsigned short* xb) {
  const int i = blockIdx.x * 256 + threadIdx.x;  // float4 index, total 2097152
  float4 v = ((const float4*)x)[i];
  ushort4 o;
  o.x = f2bf(v.x); o.y = f2bf(v.y); o.z = f2bf(v.z); o.w = f2bf(v.w);
  ((ushort4*)xb)[i] = o;
}

// ---------------- sign(w) as bf16 ±1 ----------------
__global__ __launch_bounds__(256) void sign_w(const float* w0, const float* w1,
                                              const float* w2, const float* w3,
                                              unsigned short* signs) {
  const int wi = blockIdx.y;
  const float* w = (wi == 0) ? w0 : (wi == 1) ? w1 : (wi == 2) ? w2 : w3;
  unsigned short* o = signs + (size_t)wi * NELEM_W;
  const int i = blockIdx.x * 256 + threadIdx.x;  // float4 index, total 1048576
  float4 v = ((const float4*)w)[i];
  ushort4 s;
  s.x = (v.x > 0.f) ? 0x3F80u : ((v.x < 0.f) ? 0xBF80u : 0u);
  s.y = (v.y > 0.f) ? 0x3F80u : ((v.y < 0.f) ? 0xBF80u : 0u);
  s.z = (v.z > 0.f) ? 0x3F80u : ((v.z < 0.f) ? 0xBF80u : 0u);
  s.w = (v.w > 0.f) ? 0x3F80u : ((v.w < 0.f) ? 0xBF80u : 0u);
  ((ushort4*)o)[i] = s;
}

// ---------------- GEMM: C[M=4096][N=2048] = A[M][K] * W[N][K]^T, K=2048 ----------------
// MODE 0: bf16 out, [b,h,t,d] layout (Q / K)
// MODE 1: bf16 out, transposed [b,h,d,t] layout (V^T)
// MODE 2: f32 out, row-major [M][N] (final output)
template <int MODE>
__global__ __launch_bounds__(256) void gemm_bt(const unsigned short* __restrict__ A,
                                               const unsigned short* __restrict__ W,
                                               void* __restrict__ outp,
                                               const float* __restrict__ scales,
                                               int sidx, float extra) {
  constexpr int K = 2048;
  __shared__ alignas(16) unsigned short ldsA[128 * 64];
  __shared__ alignas(16) unsigned short ldsB[128 * 64];
  const int t = threadIdx.x;
  const int wid = t >> 6, lane = t & 63;
  const int llo = lane & 15, lhi = lane >> 4;
  const int m0 = blockIdx.y * 128, n0 = blockIdx.x * 128;
  const int wm = (wid >> 1) * 64, wn = (wid & 1) * 64;
  f32x4 acc[4][4] = {};

  for (int kt = 0; kt < K / 64; ++kt) {
    const int k0 = kt * 64;
    #pragma unroll
    for (int i = 0; i < 4; ++i) {
      const int idx = i * 256 + t;
      const int row = idx >> 3, slot = idx & 7;
      const int ksw = k0 + ((slot ^ (row & 7)) << 3);
      gload_lds16(A + (size_t)(m0 + row) * K + ksw, &ldsA[(i * 256 + wid * 64) * 8]);
      gload_lds16(W + (size_t)(n0 + row) * K + ksw, &ldsB[(i * 256 + wid * 64) * 8]);
    }
    __syncthreads();
    #pragma unroll
    for (int kk = 0; kk < 2; ++kk) {
      bf16x8 a[4], b[4];
      #pragma unroll
      for (int f = 0; f < 4; ++f) {
        const int ra = wm + f * 16 + llo;
        a[f] = *(const bf16x8*)&ldsA[ra * 64 + ((kk * 4 + lhi) ^ (ra & 7)) * 8];
        const int rb = wn + f * 16 + llo;
        b[f] = *(const bf16x8*)&ldsB[rb * 64 + ((kk * 4 + lhi) ^ (rb & 7)) * 8];
      }
      #pragma unroll
      for (int fm = 0; fm < 4; ++fm)
        #pragma unroll
        for (int fn = 0; fn < 4; ++fn)
          acc[fm][fn] = __builtin_amdgcn_mfma_f32_16x16x32_bf16(a[fm], b[fn], acc[fm][fn], 0, 0, 0);
    }
    __syncthreads();
  }

  const float sc = scales[sidx] * extra;
  #pragma unroll
  for (int fm = 0; fm < 4; ++fm)
    #pragma unroll
    for (int fn = 0; fn < 4; ++fn)
      #pragma unroll
      for (int r = 0; r < 4; ++r) {
        const int row = m0 + wm + fm * 16 + lhi * 4 + r;
        const int col = n0 + wn + fn * 16 + llo;
        const float v = acc[fm][fn][r] * sc;
        if (MODE == 2) {
          ((float*)outp)[(size_t)row * D_MODEL + col] = v;
        } else {
          const int b = row >> 11, tt = row & 2047, h = col >> 7, d = col & 127;
          size_t idx;
          if (MODE == 0) idx = ((size_t)((b * NH + h) * SEQ + tt)) * HD + d;
          else           idx = ((size_t)((b * NH + h) * HD + d)) * SEQ + tt;
          ((unsigned short*)outp)[idx] = f2bf(v);
        }
      }
}

// ---------------- causal flash attention ----------------
// Q,K: [bh][t][d] bf16 (Q pre-scaled by s_q/sqrt(hd), K by s_k)
// VT:  [bh][d][t] bf16 (pre-scaled by s_v)
// O:   [b][t][h*HD+d] bf16
__global__ __launch_bounds__(64) void attn_fwd(const unsigned short* __restrict__ Q,
                                               const unsigned short* __restrict__ Kt,
                                               const unsigned short* __restrict__ VT,
                                               unsigned short* __restrict__ O) {
  __shared__ alignas(16) unsigned short plds[16 * 40];  // P tile, pad stride 40
  const int qt = blockIdx.x, bh = blockIdx.y;
  const int lane = threadIdx.x;
  const int llo = lane & 15, lhi = lane >> 4;
  const size_t bh_td = (size_t)bh * SEQ * HD;

  bf16x8 qa[4];
  {
    const unsigned short* qp = Q + bh_td + (size_t)(qt * 16 + llo) * HD + lhi * 8;
    #pragma unroll
    for (int kk = 0; kk < 4; ++kk) qa[kk] = *(const bf16x8*)(qp + kk * 32);
  }
  f32x4 oacc[8] = {};
  float m_r[4], l_r[4];
  #pragma unroll
  for (int r = 0; r < 4; ++r) { m_r[r] = -1e30f; l_r[r] = 0.f; }

  const int ntiles = (16 * qt + 47) >> 5;
  for (int kvt = 0; kvt < ntiles; ++kvt) {
    const int t0 = kvt * 32;
    f32x4 s[2] = {};
    #pragma unroll
    for (int nb = 0; nb < 2; ++nb) {
      const unsigned short* kp = Kt + bh_td + (size_t)(t0 + nb * 16 + llo) * HD + lhi * 8;
      #pragma unroll
      for (int kk = 0; kk < 4; ++kk) {
        bf16x8 kb = *(const bf16x8*)(kp + kk * 32);
        s[nb] = __builtin_amdgcn_mfma_f32_16x16x32_bf16(qa[kk], kb, s[nb], 0, 0, 0);
      }
    }
    if (t0 + 31 > qt * 16) {  // diagonal tile: mask kv > q
      #pragma unroll
      for (int nb = 0; nb < 2; ++nb)
        #pragma unroll
        for (int r = 0; r < 4; ++r)
          if (t0 + nb * 16 + llo > qt * 16 + lhi * 4 + r) s[nb][r] = -1e30f;
    }
    float mx[4], al[4], ps[4], p0[4], p1[4];
    #pragma unroll
    for (int r = 0; r < 4; ++r) mx[r] = fmaxf(s[0][r], s[1][r]);
    #pragma unroll
    for (int off = 1; off < 16; off <<= 1)
      #pragma unroll
      for (int r = 0; r < 4; ++r) mx[r] = fmaxf(mx[r], __shfl_xor(mx[r], off));
    #pragma unroll
    for (int r = 0; r < 4; ++r) {
      const float mn = fmaxf(m_r[r], mx[r]);
      al[r] = __expf(m_r[r] - mn);
      p0[r] = __expf(s[0][r] - mn);
      p1[r] = __expf(s[1][r] - mn);
      m_r[r] = mn;
      ps[r] = p0[r] + p1[r];
    }
    #pragma unroll
    for (int off = 1; off < 16; off <<= 1)
      #pragma unroll
      for (int r = 0; r < 4; ++r) ps[r] += __shfl_xor(ps[r], off);
    #pragma unroll
    for (int r = 0; r < 4; ++r) l_r[r] = l_r[r] * al[r] + ps[r];
    #pragma unroll
    for (int nb = 0; nb < 8; ++nb)
      #pragma unroll
      for (int r = 0; r < 4; ++r) oacc[nb][r] *= al[r];
    // P -> LDS (S-layout) then read back in A-layout
    #pragma unroll
    for (int r = 0; r < 4; ++r) {
      plds[(lhi * 4 + r) * 40 + llo]      = f2bf(p0[r]);
      plds[(lhi * 4 + r) * 40 + 16 + llo] = f2bf(p1[r]);
    }
    __syncthreads();
    const bf16x8 pa = *(const bf16x8*)&plds[llo * 40 + lhi * 8];
    #pragma unroll
    for (int nb = 0; nb < 8; ++nb) {
      const unsigned short* vp = VT + ((size_t)bh * HD + nb * 16 + llo) * SEQ + t0 + lhi * 8;
      const bf16x8 vb = *(const bf16x8*)vp;
      oacc[nb] = __builtin_amdgcn_mfma_f32_16x16x32_bf16(pa, vb, oacc[nb], 0, 0, 0);
    }
    __syncthreads();
  }

  const int b = bh >> 4, h = bh & 15;
  float inv[4];
  #pragma unroll
  for (int r = 0; r < 4; ++r) inv[r] = 1.f / l_r[r];
  #pragma unroll
  for (int nb = 0; nb < 8; ++nb)
    #pragma unroll
    for (int r = 0; r < 4; ++r) {
      const int qi = qt * 16 + lhi * 4 + r;
      const int d = nb * 16 + llo;
      O[((size_t)(b * SEQ + qi)) * D_MODEL + h * HD + d] = f2bf(oacc[nb][r] * inv[r]);
    }
}

extern "C" void kernel_launch(void* const* d_in, const int* in_sizes, int n_in,
                              void* d_out, int out_size, void* d_ws, size_t ws_size,
                              hipStream_t stream) {
  const float* x  = (const float*)d_in[0];
  const float* wq = (const float*)d_in[1];
  const float* wk = (const float*)d_in[2];
  const float* wv = (const float*)d_in[3];
  const float* wo = (const float*)d_in[4];

  char* ws = (char*)d_ws;
  float* scales   = (float*)ws;                   // 4 f32
  float* partials = (float*)(ws + 256);           // 4*256 f32
  unsigned short* xbf   = (unsigned short*)(ws + 8192);
  const size_t nMD = (size_t)M_TOT * D_MODEL;     // 8388608
  unsigned short* signs = xbf + nMD;
  unsigned short* Qb = signs + 4 * (size_t)NELEM_W;
  unsigned short* Kb = Qb + nMD;
  unsigned short* Vt = Kb + nMD;
  unsigned short* Ab = Vt + nMD;

  reduce1<<<dim3(256, 4), 256, 0, stream>>>(wq, wk, wv, wo, partials);
  reduce2<<<dim3(4), 256, 0, stream>>>(partials, scales);
  cvt_x<<<dim3(8192), 256, 0, stream>>>(x, xbf);
  sign_w<<<dim3(4096, 4), 256, 0, stream>>>(wq, wk, wv, wo, signs);

  // Q (scale folds 1/sqrt(128)), K, V^T
  gemm_bt<0><<<dim3(16, 32), 256, 0, stream>>>(xbf, signs,                         (void*)Qb, scales, 0, 0.08838834764831845f);
  gemm_bt<0><<<dim3(16, 32), 256, 0, stream>>>(xbf, signs + (size_t)NELEM_W,       (void*)Kb, scales, 1, 1.0f);
  gemm_bt<1><<<dim3(16, 32), 256, 0, stream>>>(xbf, signs + 2 * (size_t)NELEM_W,   (void*)Vt, scales, 2, 1.0f);

  attn_fwd<<<dim3(128, 32), 64, 0, stream>>>(Qb, Kb, Vt, Ab);

  gemm_bt<2><<<dim3(16, 32), 256, 0, stream>>>(Ab, signs + 3 * (size_t)NELEM_W, d_out, scales, 3, 1.0f);
}

// Round 2
// 388.122 us; speedup vs baseline: 1.4059x; 1.4059x over previous
//
#include <hip/hip_runtime.h>
#include <stdint.h>

#define D_MODEL 2048
#define SEQ     2048
#define BATCH   2
#define NH      16
#define HD      128
#define M_TOT   (BATCH*SEQ)          // 4096
#define NELEM_W (D_MODEL*D_MODEL)    // 4194304

typedef float f32x4 __attribute__((ext_vector_type(4)));
typedef short bf16x8 __attribute__((ext_vector_type(8)));

__device__ __forceinline__ unsigned short f2bf(float f) {
  union { float f; uint32_t u; } v; v.f = f;
  uint32_t r = v.u + 0x7FFFu + ((v.u >> 16) & 1u);
  return (unsigned short)(r >> 16);
}

__device__ __forceinline__ void gload_lds16(const unsigned short* g, unsigned short* l) {
  __builtin_amdgcn_global_load_lds(
      (const __attribute__((address_space(1))) unsigned int*)g,
      (__attribute__((address_space(3))) unsigned int*)l, 16, 0, 0);
}

// ---------------- scale reduction: s = max(mean|w|, 1e-5) ----------------
__global__ __launch_bounds__(256) void reduce1(const float* w0, const float* w1,
                                               const float* w2, const float* w3,
                                               float* partials) {
  const int wi = blockIdx.y;
  const float* w = (wi == 0) ? w0 : (wi == 1) ? w1 : (wi == 2) ? w2 : w3;
  const float4* w4 = (const float4*)w;
  const int t = threadIdx.x, bx = blockIdx.x;
  float s = 0.f;
  #pragma unroll
  for (int i = 0; i < 16; ++i) {
    float4 v = w4[(size_t)bx * 4096 + i * 256 + t];
    s += fabsf(v.x) + fabsf(v.y) + fabsf(v.z) + fabsf(v.w);
  }
  #pragma unroll
  for (int off = 32; off; off >>= 1) s += __shfl_down(s, off);
  __shared__ float sm[4];
  if ((t & 63) == 0) sm[t >> 6] = s;
  __syncthreads();
  if (t == 0) partials[wi * 256 + bx] = sm[0] + sm[1] + sm[2] + sm[3];
}

__global__ __launch_bounds__(256) void reduce2(const float* partials, float* scales) {
  const int wi = blockIdx.x, t = threadIdx.x;
  float s = partials[wi * 256 + t];
  #pragma unroll
  for (int off = 32; off; off >>= 1) s += __shfl_down(s, off);
  __shared__ float sm[4];
  if ((t & 63) == 0) sm[t >> 6] = s;
  __syncthreads();
  if (t == 0) scales[wi] = fmaxf((sm[0] + sm[1] + sm[2] + sm[3]) * (1.f / 4194304.f), 1e-5f);
}

// ---------------- x -> bf16 ----------------
__global__ __launch_bounds__(256) void cvt_x(const float* x, unsigned short* xb) {
  const int i = blockIdx.x * 256 + threadIdx.x;
  float4 v = ((const float4*)x)[i];
  ushort4 o;
  o.x = f2bf(v.x); o.y = f2bf(v.y); o.z = f2bf(v.z); o.w = f2bf(v.w);
  ((ushort4*)xb)[i] = o;
}

// ---------------- sign(w) as bf16 ±1 ----------------
__global__ __launch_bounds__(256) void sign_w(const float* w0, const float* w1,
                                              const float* w2, const float* w3,
                                              unsigned short* signs) {
  const int wi = blockIdx.y;
  const float* w = (wi == 0) ? w0 : (wi == 1) ? w1 : (wi == 2) ? w2 : w3;
  unsigned short* o = signs + (size_t)wi * NELEM_W;
  const int i = blockIdx.x * 256 + threadIdx.x;
  float4 v = ((const float4*)w)[i];
  ushort4 s;
  s.x = (v.x > 0.f) ? 0x3F80u : ((v.x < 0.f) ? 0xBF80u : 0u);
  s.y = (v.y > 0.f) ? 0x3F80u : ((v.y < 0.f) ? 0xBF80u : 0u);
  s.z = (v.z > 0.f) ? 0x3F80u : ((v.z < 0.f) ? 0xBF80u : 0u);
  s.w = (v.w > 0.f) ? 0x3F80u : ((v.w < 0.f) ? 0xBF80u : 0u);
  ((ushort4*)o)[i] = s;
}

// ---------------- GEMM: C[4096][2048] = A[M][K] * W[N][K]^T, K=2048 ----------------
template <int MODE>
__global__ __launch_bounds__(256) void gemm_bt(const unsigned short* __restrict__ A,
                                               const unsigned short* __restrict__ W,
                                               void* __restrict__ outp,
                                               const float* __restrict__ scales,
                                               int sidx, float extra) {
  constexpr int K = 2048;
  __shared__ alignas(16) unsigned short ldsA[128 * 64];
  __shared__ alignas(16) unsigned short ldsB[128 * 64];
  const int t = threadIdx.x;
  const int wid = t >> 6, lane = t & 63;
  const int llo = lane & 15, lhi = lane >> 4;
  const int m0 = blockIdx.y * 128, n0 = blockIdx.x * 128;
  const int wm = (wid >> 1) * 64, wn = (wid & 1) * 64;
  f32x4 acc[4][4] = {};

  for (int kt = 0; kt < K / 64; ++kt) {
    const int k0 = kt * 64;
    #pragma unroll
    for (int i = 0; i < 4; ++i) {
      const int idx = i * 256 + t;
      const int row = idx >> 3, slot = idx & 7;
      const int ksw = k0 + ((slot ^ (row & 7)) << 3);
      gload_lds16(A + (size_t)(m0 + row) * K + ksw, &ldsA[(i * 256 + wid * 64) * 8]);
      gload_lds16(W + (size_t)(n0 + row) * K + ksw, &ldsB[(i * 256 + wid * 64) * 8]);
    }
    __syncthreads();
    #pragma unroll
    for (int kk = 0; kk < 2; ++kk) {
      bf16x8 a[4], b[4];
      #pragma unroll
      for (int f = 0; f < 4; ++f) {
        const int ra = wm + f * 16 + llo;
        a[f] = *(const bf16x8*)&ldsA[ra * 64 + ((kk * 4 + lhi) ^ (ra & 7)) * 8];
        const int rb = wn + f * 16 + llo;
        b[f] = *(const bf16x8*)&ldsB[rb * 64 + ((kk * 4 + lhi) ^ (rb & 7)) * 8];
      }
      #pragma unroll
      for (int fm = 0; fm < 4; ++fm)
        #pragma unroll
        for (int fn = 0; fn < 4; ++fn)
          acc[fm][fn] = __builtin_amdgcn_mfma_f32_16x16x32_bf16(a[fm], b[fn], acc[fm][fn], 0, 0, 0);
    }
    __syncthreads();
  }

  const float sc = scales[sidx] * extra;
  #pragma unroll
  for (int fm = 0; fm < 4; ++fm)
    #pragma unroll
    for (int fn = 0; fn < 4; ++fn)
      #pragma unroll
      for (int r = 0; r < 4; ++r) {
        const int row = m0 + wm + fm * 16 + lhi * 4 + r;
        const int col = n0 + wn + fn * 16 + llo;
        const float v = acc[fm][fn][r] * sc;
        if (MODE == 2) {
          ((float*)outp)[(size_t)row * D_MODEL + col] = v;
        } else {
          const int b = row >> 11, tt = row & 2047, h = col >> 7, d = col & 127;
          size_t idx;
          if (MODE == 0) idx = ((size_t)((b * NH + h) * SEQ + tt)) * HD + d;
          else           idx = ((size_t)((b * NH + h) * HD + d)) * SEQ + tt;
          ((unsigned short*)outp)[idx] = f2bf(v);
        }
      }
}

// ---------------- causal flash attention (4-wave, paired q-groups) ----------------
// Q,K: [bh][t][d] bf16 (Q pre-scaled by s_q/sqrt(hd), K by s_k); VT: [bh][d][t]
// O: [b][t][h*HD+d] bf16
// Block p handles q-groups {p, 31-p} (64 rows each) -> uniform 33 KV tiles/block.
__global__ __launch_bounds__(256) void attn_fwd(const unsigned short* __restrict__ Q,
                                                const unsigned short* __restrict__ Kt,
                                                const unsigned short* __restrict__ VT,
                                                unsigned short* __restrict__ O) {
  __shared__ alignas(16) unsigned short ldsK[2][64 * 128];  // 32 KB dbuf
  __shared__ alignas(16) unsigned short plds[4][16 * 64];   // 8 KB, per-wave P
  const int t = threadIdx.x;
  const int wid = t >> 6, lane = t & 63;
  const int llo = lane & 15, lhi = lane >> 4;
  const int p = blockIdx.x, bh = blockIdx.y;
  const size_t bh_td = (size_t)bh * SEQ * HD;
  unsigned short* pw = &plds[wid][0];

  auto stage = [&](int buf, int t0) {
    #pragma unroll
    for (int i = 0; i < 4; ++i) {
      const int idx = i * 256 + t;
      const int row = idx >> 4, slot = idx & 15;
      gload_lds16(Kt + bh_td + (size_t)(t0 + row) * HD + ((slot ^ (row & 15)) << 3),
                  &ldsK[buf][(size_t)(i * 256 + wid * 64) * 8]);
    }
  };

  int cur = 0;
  const int qgs[2] = { p, 31 - p };
  stage(0, 0);  // prologue: group0 tile0

  for (int g = 0; g < 2; ++g) {
    const int qbase = qgs[g] * 64;
    const int nt = qgs[g] + 1;
    bf16x8 qa[4];
    {
      const unsigned short* qp = Q + bh_td + (size_t)(qbase + wid * 16 + llo) * HD + lhi * 8;
      #pragma unroll
      for (int kk = 0; kk < 4; ++kk) qa[kk] = *(const bf16x8*)(qp + kk * 32);
    }
    f32x4 oacc[8] = {};
    float m_r[4], l_r[4];
    #pragma unroll
    for (int r = 0; r < 4; ++r) { m_r[r] = -1e30f; l_r[r] = 0.f; }

    for (int kvt = 0; kvt < nt; ++kvt) {
      __syncthreads();  // drains vmcnt: ldsK[cur] ready; all prior ldsK[cur^1] reads done
      // issue next stage into other buffer (hidden under this tile's compute)
      if (!(g == 1 && kvt == nt - 1)) {
        const int nxt_t0 = (kvt + 1 < nt) ? (kvt + 1) * 64 : 0;  // else group1 tile0
        stage(cur ^ 1, nxt_t0);
      }
      // ---- QK^T ----
      f32x4 s[4] = {};
      __builtin_amdgcn_s_setprio(1);
      #pragma unroll
      for (int nb = 0; nb < 4; ++nb) {
        const int row = nb * 16 + llo;
        #pragma unroll
        for (int kk = 0; kk < 4; ++kk) {
          const bf16x8 kb = *(const bf16x8*)&ldsK[cur][row * 128 + (((kk * 4 + lhi) ^ llo) << 3)];
          s[nb] = __builtin_amdgcn_mfma_f32_16x16x32_bf16(qa[kk], kb, s[nb], 0, 0, 0);
        }
      }
      __builtin_amdgcn_s_setprio(0);
      // ---- causal mask (last tile is the diagonal) ----
      if (kvt == nt - 1) {
        #pragma unroll
        for (int nb = 0; nb < 4; ++nb)
          #pragma unroll
          for (int r = 0; r < 4; ++r)
            if (nb * 16 + llo > wid * 16 + lhi * 4 + r) s[nb][r] = -1e30f;
      }
      // ---- online softmax ----
      float mx[4], al[4], ps[4];
      #pragma unroll
      for (int r = 0; r < 4; ++r)
        mx[r] = fmaxf(fmaxf(s[0][r], s[1][r]), fmaxf(s[2][r], s[3][r]));
      #pragma unroll
      for (int off = 1; off < 16; off <<= 1)
        #pragma unroll
        for (int r = 0; r < 4; ++r) mx[r] = fmaxf(mx[r], __shfl_xor(mx[r], off));
      #pragma unroll
      for (int r = 0; r < 4; ++r) {
        const float mn = fmaxf(m_r[r], mx[r]);
        al[r] = __expf(m_r[r] - mn);
        m_r[r] = mn;
        #pragma unroll
        for (int nb = 0; nb < 4; ++nb) s[nb][r] = __expf(s[nb][r] - mn);
        ps[r] = (s[0][r] + s[1][r]) + (s[2][r] + s[3][r]);
      }
      #pragma unroll
      for (int off = 1; off < 16; off <<= 1)
        #pragma unroll
        for (int r = 0; r < 4; ++r) ps[r] += __shfl_xor(ps[r], off);
      #pragma unroll
      for (int r = 0; r < 4; ++r) l_r[r] = l_r[r] * al[r] + ps[r];
      #pragma unroll
      for (int nb = 0; nb < 8; ++nb)
        #pragma unroll
        for (int r = 0; r < 4; ++r) oacc[nb][r] *= al[r];
      // ---- P -> per-wave LDS (swizzled slots), read back as A-fragments ----
      #pragma unroll
      for (int nb = 0; nb < 4; ++nb)
        #pragma unroll
        for (int r = 0; r < 4; ++r) {
          const int q = lhi * 4 + r;
          const int slot = nb * 2 + (llo >> 3);
          pw[q * 64 + ((slot ^ (q & 7)) << 3) + (llo & 7)] = f2bf(s[nb][r]);
        }
      asm volatile("s_waitcnt lgkmcnt(0)" ::: "memory");
      __builtin_amdgcn_sched_barrier(0);
      const bf16x8 pa0 = *(const bf16x8*)&pw[llo * 64 + ((lhi ^ (llo & 7)) << 3)];
      const bf16x8 pa1 = *(const bf16x8*)&pw[llo * 64 + (((4 + lhi) ^ (llo & 7)) << 3)];
      // ---- PV ----
      const int t0 = kvt * 64;
      __builtin_amdgcn_s_setprio(1);
      #pragma unroll
      for (int db = 0; db < 8; ++db) {
        const unsigned short* vp = VT + ((size_t)bh * HD + db * 16 + llo) * SEQ + t0 + lhi * 8;
        const bf16x8 vb0 = *(const bf16x8*)vp;
        const bf16x8 vb1 = *(const bf16x8*)(vp + 32);
        oacc[db] = __builtin_amdgcn_mfma_f32_16x16x32_bf16(pa0, vb0, oacc[db], 0, 0, 0);
        oacc[db] = __builtin_amdgcn_mfma_f32_16x16x32_bf16(pa1, vb1, oacc[db], 0, 0, 0);
      }
      __builtin_amdgcn_s_setprio(0);
      cur ^= 1;
    }
    // ---- epilogue for this group ----
    const int b = bh >> 4, h = bh & 15;
    float inv[4];
    #pragma unroll
    for (int r = 0; r < 4; ++r) inv[r] = 1.f / l_r[r];
    #pragma unroll
    for (int db = 0; db < 8; ++db)
      #pragma unroll
      for (int r = 0; r < 4; ++r) {
        const int qi = qbase + wid * 16 + lhi * 4 + r;
        const int d = db * 16 + llo;
        O[((size_t)(b * SEQ + qi)) * D_MODEL + h * HD + d] = f2bf(oacc[db][r] * inv[r]);
      }
  }
}

extern "C" void kernel_launch(void* const* d_in, const int* in_sizes, int n_in,
                              void* d_out, int out_size, void* d_ws, size_t ws_size,
                              hipStream_t stream) {
  const float* x  = (const float*)d_in[0];
  const float* wq = (const float*)d_in[1];
  const float* wk = (const float*)d_in[2];
  const float* wv = (const float*)d_in[3];
  const float* wo = (const float*)d_in[4];

  char* ws = (char*)d_ws;
  float* scales   = (float*)ws;
  float* partials = (float*)(ws + 256);
  unsigned short* xbf   = (unsigned short*)(ws + 8192);
  const size_t nMD = (size_t)M_TOT * D_MODEL;
  unsigned short* signs = xbf + nMD;
  unsigned short* Qb = signs + 4 * (size_t)NELEM_W;
  unsigned short* Kb = Qb + nMD;
  unsigned short* Vt = Kb + nMD;
  unsigned short* Ab = Vt + nMD;

  reduce1<<<dim3(256, 4), 256, 0, stream>>>(wq, wk, wv, wo, partials);
  reduce2<<<dim3(4), 256, 0, stream>>>(partials, scales);
  cvt_x<<<dim3(8192), 256, 0, stream>>>(x, xbf);
  sign_w<<<dim3(4096, 4), 256, 0, stream>>>(wq, wk, wv, wo, signs);

  gemm_bt<0><<<dim3(16, 32), 256, 0, stream>>>(xbf, signs,                       (void*)Qb, scales, 0, 0.08838834764831845f);
  gemm_bt<0><<<dim3(16, 32), 256, 0, stream>>>(xbf, signs + (size_t)NELEM_W,     (void*)Kb, scales, 1, 1.0f);
  gemm_bt<1><<<dim3(16, 32), 256, 0, stream>>>(xbf, signs + 2 * (size_t)NELEM_W, (void*)Vt, scales, 2, 1.0f);

  attn_fwd<<<dim3(16, 32), 256, 0, stream>>>(Qb, Kb, Vt, Ab);

  gemm_bt<2><<<dim3(16, 32), 256, 0, stream>>>(Ab, signs + 3 * (size_t)NELEM_W, d_out, scales, 3, 1.0f);
}

// Round 3
// 321.337 us; speedup vs baseline: 1.6982x; 1.2078x over previous
//
#include <hip/hip_runtime.h>
#include <stdint.h>

#define D_MODEL 2048
#define SEQ     2048
#define BATCH   2
#define NH      16
#define HD      128
#define M_TOT   (BATCH*SEQ)          // 4096
#define NELEM_W (D_MODEL*D_MODEL)    // 4194304

typedef float f32x4 __attribute__((ext_vector_type(4)));
typedef short bf16x8 __attribute__((ext_vector_type(8)));

__device__ __forceinline__ unsigned short f2bf(float f) {
  union { float f; uint32_t u; } v; v.f = f;
  uint32_t r = v.u + 0x7FFFu + ((v.u >> 16) & 1u);
  return (unsigned short)(r >> 16);
}

__device__ __forceinline__ void gload_lds16(const unsigned short* g, unsigned short* l) {
  __builtin_amdgcn_global_load_lds(
      (const __attribute__((address_space(1))) unsigned int*)g,
      (__attribute__((address_space(3))) unsigned int*)l, 16, 0, 0);
}

// ---------------- scale reduction: s = max(mean|w|, 1e-5) ----------------
__global__ __launch_bounds__(256) void reduce1(const float* w0, const float* w1,
                                               const float* w2, const float* w3,
                                               float* partials) {
  const int wi = blockIdx.y;
  const float* w = (wi == 0) ? w0 : (wi == 1) ? w1 : (wi == 2) ? w2 : w3;
  const float4* w4 = (const float4*)w;
  const int t = threadIdx.x, bx = blockIdx.x;
  float s = 0.f;
  #pragma unroll
  for (int i = 0; i < 16; ++i) {
    float4 v = w4[(size_t)bx * 4096 + i * 256 + t];
    s += fabsf(v.x) + fabsf(v.y) + fabsf(v.z) + fabsf(v.w);
  }
  #pragma unroll
  for (int off = 32; off; off >>= 1) s += __shfl_down(s, off);
  __shared__ float sm[4];
  if ((t & 63) == 0) sm[t >> 6] = s;
  __syncthreads();
  if (t == 0) partials[wi * 256 + bx] = sm[0] + sm[1] + sm[2] + sm[3];
}

__global__ __launch_bounds__(256) void reduce2(const float* partials, float* scales) {
  const int wi = blockIdx.x, t = threadIdx.x;
  float s = partials[wi * 256 + t];
  #pragma unroll
  for (int off = 32; off; off >>= 1) s += __shfl_down(s, off);
  __shared__ float sm[4];
  if ((t & 63) == 0) sm[t >> 6] = s;
  __syncthreads();
  if (t == 0) scales[wi] = fmaxf((sm[0] + sm[1] + sm[2] + sm[3]) * (1.f / 4194304.f), 1e-5f);
}

// ---------------- x -> bf16 ----------------
__global__ __launch_bounds__(256) void cvt_x(const float* x, unsigned short* xb) {
  const int i = blockIdx.x * 256 + threadIdx.x;
  float4 v = ((const float4*)x)[i];
  ushort4 o;
  o.x = f2bf(v.x); o.y = f2bf(v.y); o.z = f2bf(v.z); o.w = f2bf(v.w);
  ((ushort4*)xb)[i] = o;
}

// ---------------- sign(w) as bf16 ±1 ----------------
__global__ __launch_bounds__(256) void sign_w(const float* w0, const float* w1,
                                              const float* w2, const float* w3,
                                              unsigned short* signs) {
  const int wi = blockIdx.y;
  const float* w = (wi == 0) ? w0 : (wi == 1) ? w1 : (wi == 2) ? w2 : w3;
  unsigned short* o = signs + (size_t)wi * NELEM_W;
  const int i = blockIdx.x * 256 + threadIdx.x;
  float4 v = ((const float4*)w)[i];
  ushort4 s;
  s.x = (v.x > 0.f) ? 0x3F80u : ((v.x < 0.f) ? 0xBF80u : 0u);
  s.y = (v.y > 0.f) ? 0x3F80u : ((v.y < 0.f) ? 0xBF80u : 0u);
  s.z = (v.z > 0.f) ? 0x3F80u : ((v.z < 0.f) ? 0xBF80u : 0u);
  s.w = (v.w > 0.f) ? 0x3F80u : ((v.w < 0.f) ? 0xBF80u : 0u);
  ((ushort4*)o)[i] = s;
}

// ---------------- GEMM: C[4096][2048] = A[M][K] * W[N][K]^T, K=2048 ----------------
template <int MODE>
__global__ __launch_bounds__(256) void gemm_bt(const unsigned short* __restrict__ A,
                                               const unsigned short* __restrict__ W,
                                               void* __restrict__ outp,
                                               const float* __restrict__ scales,
                                               int sidx, float extra) {
  constexpr int K = 2048;
  __shared__ alignas(16) unsigned short ldsA[128 * 64];
  __shared__ alignas(16) unsigned short ldsB[128 * 64];
  const int t = threadIdx.x;
  const int wid = t >> 6, lane = t & 63;
  const int llo = lane & 15, lhi = lane >> 4;
  const int m0 = blockIdx.y * 128, n0 = blockIdx.x * 128;
  const int wm = (wid >> 1) * 64, wn = (wid & 1) * 64;
  f32x4 acc[4][4] = {};

  for (int kt = 0; kt < K / 64; ++kt) {
    const int k0 = kt * 64;
    #pragma unroll
    for (int i = 0; i < 4; ++i) {
      const int idx = i * 256 + t;
      const int row = idx >> 3, slot = idx & 7;
      const int ksw = k0 + ((slot ^ (row & 7)) << 3);
      gload_lds16(A + (size_t)(m0 + row) * K + ksw, &ldsA[(i * 256 + wid * 64) * 8]);
      gload_lds16(W + (size_t)(n0 + row) * K + ksw, &ldsB[(i * 256 + wid * 64) * 8]);
    }
    __syncthreads();
    #pragma unroll
    for (int kk = 0; kk < 2; ++kk) {
      bf16x8 a[4], b[4];
      #pragma unroll
      for (int f = 0; f < 4; ++f) {
        const int ra = wm + f * 16 + llo;
        a[f] = *(const bf16x8*)&ldsA[ra * 64 + ((kk * 4 + lhi) ^ (ra & 7)) * 8];
        const int rb = wn + f * 16 + llo;
        b[f] = *(const bf16x8*)&ldsB[rb * 64 + ((kk * 4 + lhi) ^ (rb & 7)) * 8];
      }
      #pragma unroll
      for (int fm = 0; fm < 4; ++fm)
        #pragma unroll
        for (int fn = 0; fn < 4; ++fn)
          acc[fm][fn] = __builtin_amdgcn_mfma_f32_16x16x32_bf16(a[fm], b[fn], acc[fm][fn], 0, 0, 0);
    }
    __syncthreads();
  }

  const float sc = scales[sidx] * extra;
  #pragma unroll
  for (int fm = 0; fm < 4; ++fm)
    #pragma unroll
    for (int fn = 0; fn < 4; ++fn)
      #pragma unroll
      for (int r = 0; r < 4; ++r) {
        const int row = m0 + wm + fm * 16 + lhi * 4 + r;
        const int col = n0 + wn + fn * 16 + llo;
        const float v = acc[fm][fn][r] * sc;
        if (MODE == 2) {
          ((float*)outp)[(size_t)row * D_MODEL + col] = v;
        } else {
          const int b = row >> 11, tt = row & 2047, h = col >> 7, d = col & 127;
          size_t idx;
          if (MODE == 0) idx = ((size_t)((b * NH + h) * SEQ + tt)) * HD + d;
          else           idx = ((size_t)((b * NH + h) * HD + d)) * SEQ + tt;
          ((unsigned short*)outp)[idx] = f2bf(v);
        }
      }
}

// ---------------- causal flash attention (8-wave, QBLK=128, K+V staged) ----------------
// Q,K: [bh][t][d] bf16 (Q pre-scaled by s_q/sqrt(hd), K by s_k); VT: [bh][d][t]
// O: [b][t][h*HD+d] bf16
// Block (bh, yg): q-group g = 15-yg (128 rows), nt = 2g+2 KV tiles of 64.
__global__ __launch_bounds__(512, 4) void attn_fwd(const unsigned short* __restrict__ Q,
                                                   const unsigned short* __restrict__ Kt,
                                                   const unsigned short* __restrict__ VT,
                                                   unsigned short* __restrict__ O) {
  // per buffer: K tile [64 kv][128 d] at [0,8192), V tile [128 d][64 t] at [8192,16384)
  __shared__ alignas(16) unsigned short lds[2][16384];   // 64 KB
  __shared__ alignas(16) unsigned short plds[8][1024];   // 16 KB, per-wave P
  const int t = threadIdx.x;
  const int wid = t >> 6, lane = t & 63;
  const int llo = lane & 15, lhi = lane >> 4;
  const int bh = blockIdx.x;
  const int g = 15 - (int)blockIdx.y;    // longest first (LPT)
  const int qbase = g * 128;
  const int nt = 2 * g + 2;
  const size_t bh_td = (size_t)bh * SEQ * HD;
  const size_t bh_dt = (size_t)bh * HD * SEQ;
  unsigned short* pw = &plds[wid][0];
  const int fvl = (llo & 7) ^ ((llo & 8) >> 1);  // V swizzle key for read rows d=db*16+llo

  auto stage = [&](int buf, int j) {
    const int t0 = j * 64;
    #pragma unroll
    for (int i = 0; i < 2; ++i) {       // K: 1024 chunks of 16B
      const int c = i * 512 + t;
      const int row = c >> 4, slot = c & 15;
      gload_lds16(Kt + bh_td + (size_t)(t0 + row) * HD + ((slot ^ (row & 15)) << 3),
                  &lds[buf][(size_t)(i * 512 + wid * 64) * 8]);
    }
    #pragma unroll
    for (int i = 0; i < 2; ++i) {       // V: 1024 chunks of 16B
      const int c = i * 512 + t;
      const int vrow = c >> 3, vslot = c & 7;
      const int fv = (vrow & 7) ^ ((vrow & 8) >> 1);
      gload_lds16(VT + bh_dt + (size_t)vrow * SEQ + t0 + ((vslot ^ fv) << 3),
                  &lds[buf][8192 + (size_t)(i * 512 + wid * 64) * 8]);
    }
  };

  // Q fragments: wave wid owns q rows qbase + wid*16 + [0,16)
  bf16x8 qa[4];
  {
    const unsigned short* qp = Q + bh_td + (size_t)(qbase + wid * 16 + llo) * HD + lhi * 8;
    #pragma unroll
    for (int kk = 0; kk < 4; ++kk) qa[kk] = *(const bf16x8*)(qp + kk * 32);
  }
  f32x4 oacc[8] = {};
  float m_r[4], l_r[4];
  #pragma unroll
  for (int r = 0; r < 4; ++r) { m_r[r] = -1e30f; l_r[r] = 0.f; }

  stage(0, 0);
  for (int j = 0; j < nt; ++j) {
    const int cur = j & 1;
    __syncthreads();                    // staged lds[cur] ready; prior reads of lds[cur] done
    if (j + 1 < nt) stage(cur ^ 1, j + 1);
    // ---- QK^T ----
    f32x4 s[4] = {};
    __builtin_amdgcn_s_setprio(1);
    #pragma unroll
    for (int nb = 0; nb < 4; ++nb) {
      const int row = nb * 16 + llo;
      #pragma unroll
      for (int kk = 0; kk < 4; ++kk) {
        const bf16x8 kb = *(const bf16x8*)&lds[cur][row * 128 + (((kk * 4 + lhi) ^ llo) << 3)];
        s[nb] = __builtin_amdgcn_mfma_f32_16x16x32_bf16(qa[kk], kb, s[nb], 0, 0, 0);
      }
    }
    __builtin_amdgcn_s_setprio(0);
    // ---- causal mask (only the last two tiles touch the diagonal band) ----
    if (j >= nt - 2) {
      #pragma unroll
      for (int nb = 0; nb < 4; ++nb)
        #pragma unroll
        for (int r = 0; r < 4; ++r)
          if (j * 64 + nb * 16 + llo > qbase + wid * 16 + lhi * 4 + r) s[nb][r] = -1e30f;
    }
    // ---- online softmax ----
    float mx[4], al[4], ps[4];
    #pragma unroll
    for (int r = 0; r < 4; ++r)
      mx[r] = fmaxf(fmaxf(s[0][r], s[1][r]), fmaxf(s[2][r], s[3][r]));
    #pragma unroll
    for (int off = 1; off < 16; off <<= 1)
      #pragma unroll
      for (int r = 0; r < 4; ++r) mx[r] = fmaxf(mx[r], __shfl_xor(mx[r], off));
    #pragma unroll
    for (int r = 0; r < 4; ++r) {
      const float mn = fmaxf(m_r[r], mx[r]);
      al[r] = __expf(m_r[r] - mn);
      m_r[r] = mn;
      #pragma unroll
      for (int nb = 0; nb < 4; ++nb) s[nb][r] = __expf(s[nb][r] - mn);
      ps[r] = (s[0][r] + s[1][r]) + (s[2][r] + s[3][r]);
    }
    #pragma unroll
    for (int off = 1; off < 16; off <<= 1)
      #pragma unroll
      for (int r = 0; r < 4; ++r) ps[r] += __shfl_xor(ps[r], off);
    #pragma unroll
    for (int r = 0; r < 4; ++r) l_r[r] = l_r[r] * al[r] + ps[r];
    #pragma unroll
    for (int nb = 0; nb < 8; ++nb)
      #pragma unroll
      for (int r = 0; r < 4; ++r) oacc[nb][r] *= al[r];
    // ---- P -> per-wave LDS (swizzled), read back as A-fragments ----
    #pragma unroll
    for (int nb = 0; nb < 4; ++nb)
      #pragma unroll
      for (int r = 0; r < 4; ++r) {
        const int q = lhi * 4 + r;
        const int slot = nb * 2 + (llo >> 3);
        pw[q * 64 + ((slot ^ (q & 7)) << 3) + (llo & 7)] = f2bf(s[nb][r]);
      }
    asm volatile("s_waitcnt lgkmcnt(0)" ::: "memory");
    __builtin_amdgcn_sched_barrier(0);
    const bf16x8 pa0 = *(const bf16x8*)&pw[llo * 64 + ((lhi ^ (llo & 7)) << 3)];
    const bf16x8 pa1 = *(const bf16x8*)&pw[llo * 64 + (((4 + lhi) ^ (llo & 7)) << 3)];
    // ---- PV (V from LDS, staged+swizzled) ----
    __builtin_amdgcn_s_setprio(1);
    #pragma unroll
    for (int db = 0; db < 8; ++db) {
      const unsigned short* vbp = &lds[cur][8192 + (db * 16 + llo) * 64];
      const bf16x8 vb0 = *(const bf16x8*)&vbp[(lhi ^ fvl) << 3];
      const bf16x8 vb1 = *(const bf16x8*)&vbp[((4 + lhi) ^ fvl) << 3];
      oacc[db] = __builtin_amdgcn_mfma_f32_16x16x32_bf16(pa0, vb0, oacc[db], 0, 0, 0);
      oacc[db] = __builtin_amdgcn_mfma_f32_16x16x32_bf16(pa1, vb1, oacc[db], 0, 0, 0);
    }
    __builtin_amdgcn_s_setprio(0);
  }

  // ---- epilogue ----
  const int b = bh >> 4, h = bh & 15;
  float inv[4];
  #pragma unroll
  for (int r = 0; r < 4; ++r) inv[r] = 1.f / l_r[r];
  #pragma unroll
  for (int db = 0; db < 8; ++db)
    #pragma unroll
    for (int r = 0; r < 4; ++r) {
      const int qi = qbase + wid * 16 + lhi * 4 + r;
      const int d = db * 16 + llo;
      O[((size_t)(b * SEQ + qi)) * D_MODEL + h * HD + d] = f2bf(oacc[db][r] * inv[r]);
    }
}

extern "C" void kernel_launch(void* const* d_in, const int* in_sizes, int n_in,
                              void* d_out, int out_size, void* d_ws, size_t ws_size,
                              hipStream_t stream) {
  const float* x  = (const float*)d_in[0];
  const float* wq = (const float*)d_in[1];
  const float* wk = (const float*)d_in[2];
  const float* wv = (const float*)d_in[3];
  const float* wo = (const float*)d_in[4];

  char* ws = (char*)d_ws;
  float* scales   = (float*)ws;
  float* partials = (float*)(ws + 256);
  unsigned short* xbf   = (unsigned short*)(ws + 8192);
  const size_t nMD = (size_t)M_TOT * D_MODEL;
  unsigned short* signs = xbf + nMD;
  unsigned short* Qb = signs + 4 * (size_t)NELEM_W;
  unsigned short* Kb = Qb + nMD;
  unsigned short* Vt = Kb + nMD;
  unsigned short* Ab = Vt + nMD;

  reduce1<<<dim3(256, 4), 256, 0, stream>>>(wq, wk, wv, wo, partials);
  reduce2<<<dim3(4), 256, 0, stream>>>(partials, scales);
  cvt_x<<<dim3(8192), 256, 0, stream>>>(x, xbf);
  sign_w<<<dim3(4096, 4), 256, 0, stream>>>(wq, wk, wv, wo, signs);

  gemm_bt<0><<<dim3(16, 32), 256, 0, stream>>>(xbf, signs,                       (void*)Qb, scales, 0, 0.08838834764831845f);
  gemm_bt<0><<<dim3(16, 32), 256, 0, stream>>>(xbf, signs + (size_t)NELEM_W,     (void*)Kb, scales, 1, 1.0f);
  gemm_bt<1><<<dim3(16, 32), 256, 0, stream>>>(xbf, signs + 2 * (size_t)NELEM_W, (void*)Vt, scales, 2, 1.0f);

  attn_fwd<<<dim3(32, 16), 512, 0, stream>>>(Qb, Kb, Vt, Ab);

  gemm_bt<2><<<dim3(16, 32), 256, 0, stream>>>(Ab, signs + 3 * (size_t)NELEM_W, d_out, scales, 3, 1.0f);
}

// Round 4
// 261.887 us; speedup vs baseline: 2.0836x; 1.2270x over previous
//
#include <hip/hip_runtime.h>
#include <stdint.h>

#define D_MODEL 2048
#define SEQ     2048
#define BATCH   2
#define NH      16
#define HD      128
#define M_TOT   (BATCH*SEQ)          // 4096
#define NELEM_W (D_MODEL*D_MODEL)    // 4194304

typedef float f32x4 __attribute__((ext_vector_type(4)));
typedef short bf16x8 __attribute__((ext_vector_type(8)));

__device__ __forceinline__ unsigned short f2bf(float f) {
  union { float f; uint32_t u; } v; v.f = f;
  uint32_t r = v.u + 0x7FFFu + ((v.u >> 16) & 1u);
  return (unsigned short)(r >> 16);
}

__device__ __forceinline__ void gload_lds16(const unsigned short* g, unsigned short* l) {
  __builtin_amdgcn_global_load_lds(
      (const __attribute__((address_space(1))) unsigned int*)g,
      (__attribute__((address_space(3))) unsigned int*)l, 16, 0, 0);
}

// ---------------- sign(w) as bf16 ±1, fused |w| partial reduction ----------------
__global__ __launch_bounds__(256) void sign_w(const float* w0, const float* w1,
                                              const float* w2, const float* w3,
                                              unsigned short* signs, float* partials) {
  const int wi = blockIdx.y;
  const float* w = (wi == 0) ? w0 : (wi == 1) ? w1 : (wi == 2) ? w2 : w3;
  unsigned short* o = signs + (size_t)wi * NELEM_W;
  const int t = threadIdx.x;
  const int i = blockIdx.x * 256 + t;
  float4 v = ((const float4*)w)[i];
  ushort4 s;
  s.x = (v.x > 0.f) ? 0x3F80u : ((v.x < 0.f) ? 0xBF80u : 0u);
  s.y = (v.y > 0.f) ? 0x3F80u : ((v.y < 0.f) ? 0xBF80u : 0u);
  s.z = (v.z > 0.f) ? 0x3F80u : ((v.z < 0.f) ? 0xBF80u : 0u);
  s.w = (v.w > 0.f) ? 0x3F80u : ((v.w < 0.f) ? 0xBF80u : 0u);
  ((ushort4*)o)[i] = s;
  float a = fabsf(v.x) + fabsf(v.y) + fabsf(v.z) + fabsf(v.w);
  #pragma unroll
  for (int off = 32; off; off >>= 1) a += __shfl_down(a, off);
  __shared__ float sm[4];
  if ((t & 63) == 0) sm[t >> 6] = a;
  __syncthreads();
  if (t == 0) partials[wi * 4096 + blockIdx.x] = sm[0] + sm[1] + sm[2] + sm[3];
}

__global__ __launch_bounds__(256) void reduce2(const float* partials, float* scales) {
  const int wi = blockIdx.x, t = threadIdx.x;
  float s = 0.f;
  #pragma unroll
  for (int i = 0; i < 16; ++i) s += partials[wi * 4096 + i * 256 + t];
  #pragma unroll
  for (int off = 32; off; off >>= 1) s += __shfl_down(s, off);
  __shared__ float sm[4];
  if ((t & 63) == 0) sm[t >> 6] = s;
  __syncthreads();
  if (t == 0) scales[wi] = fmaxf((sm[0] + sm[1] + sm[2] + sm[3]) * (1.f / 4194304.f), 1e-5f);
}

// ---------------- x -> bf16 ----------------
__global__ __launch_bounds__(256) void cvt_x(const float* x, unsigned short* xb) {
  const int i = blockIdx.x * 256 + threadIdx.x;
  float4 v = ((const float4*)x)[i];
  ushort4 o;
  o.x = f2bf(v.x); o.y = f2bf(v.y); o.z = f2bf(v.z); o.w = f2bf(v.w);
  ((ushort4*)xb)[i] = o;
}

// ---------------- GEMM: C[4096][2048] = A[M][K] * W[N][K]^T, K=2048 ----------------
template <int MODE>
__global__ __launch_bounds__(256) void gemm_bt(const unsigned short* __restrict__ A,
                                               const unsigned short* __restrict__ W,
                                               void* __restrict__ outp,
                                               const float* __restrict__ scales,
                                               int sidx, float extra) {
  constexpr int K = 2048;
  __shared__ alignas(16) unsigned short ldsA[128 * 64];
  __shared__ alignas(16) unsigned short ldsB[128 * 64];
  const int t = threadIdx.x;
  const int wid = t >> 6, lane = t & 63;
  const int llo = lane & 15, lhi = lane >> 4;
  const int m0 = blockIdx.y * 128, n0 = blockIdx.x * 128;
  const int wm = (wid >> 1) * 64, wn = (wid & 1) * 64;
  f32x4 acc[4][4] = {};

  for (int kt = 0; kt < K / 64; ++kt) {
    const int k0 = kt * 64;
    #pragma unroll
    for (int i = 0; i < 4; ++i) {
      const int idx = i * 256 + t;
      const int row = idx >> 3, slot = idx & 7;
      const int ksw = k0 + ((slot ^ (row & 7)) << 3);
      gload_lds16(A + (size_t)(m0 + row) * K + ksw, &ldsA[(i * 256 + wid * 64) * 8]);
      gload_lds16(W + (size_t)(n0 + row) * K + ksw, &ldsB[(i * 256 + wid * 64) * 8]);
    }
    __syncthreads();
    #pragma unroll
    for (int kk = 0; kk < 2; ++kk) {
      bf16x8 a[4], b[4];
      #pragma unroll
      for (int f = 0; f < 4; ++f) {
        const int ra = wm + f * 16 + llo;
        a[f] = *(const bf16x8*)&ldsA[ra * 64 + ((kk * 4 + lhi) ^ (ra & 7)) * 8];
        const int rb = wn + f * 16 + llo;
        b[f] = *(const bf16x8*)&ldsB[rb * 64 + ((kk * 4 + lhi) ^ (rb & 7)) * 8];
      }
      #pragma unroll
      for (int fm = 0; fm < 4; ++fm)
        #pragma unroll
        for (int fn = 0; fn < 4; ++fn)
          acc[fm][fn] = __builtin_amdgcn_mfma_f32_16x16x32_bf16(a[fm], b[fn], acc[fm][fn], 0, 0, 0);
    }
    __syncthreads();
  }

  const float sc = scales[sidx] * extra;
  #pragma unroll
  for (int fm = 0; fm < 4; ++fm)
    #pragma unroll
    for (int fn = 0; fn < 4; ++fn)
      #pragma unroll
      for (int r = 0; r < 4; ++r) {
        const int row = m0 + wm + fm * 16 + lhi * 4 + r;
        const int col = n0 + wn + fn * 16 + llo;
        const float v = acc[fm][fn][r] * sc;
        if (MODE == 2) {
          ((float*)outp)[(size_t)row * D_MODEL + col] = v;
        } else {
          const int b = row >> 11, tt = row & 2047, h = col >> 7, d = col & 127;
          size_t idx;
          if (MODE == 0) idx = ((size_t)((b * NH + h) * SEQ + tt)) * HD + d;
          else           idx = ((size_t)((b * NH + h) * HD + d)) * SEQ + tt;
          ((unsigned short*)outp)[idx] = f2bf(v);
        }
      }
}

// ---------------- causal flash attention (8-wave, QBLK=128, swapped QK^T) ----------------
// Q,K: [bh][t][d] bf16 (Q pre-scaled by s_q/sqrt(hd), K by s_k); VT: [bh][d][t] (s_v folded)
// O: [b][t][h*HD+d] bf16
// 1D grid 512: j<256 -> (bh=j&31, g=15-(j>>5)); j>=256 -> (bh, g=(j-256)>>5).
// Blocks j and j+256 pair g with 15-g -> uniform 34 tiles per CU (2 blocks/CU).
__global__ __launch_bounds__(512, 4) void attn_fwd(const unsigned short* __restrict__ Q,
                                                   const unsigned short* __restrict__ Kt,
                                                   const unsigned short* __restrict__ VT,
                                                   unsigned short* __restrict__ O) {
  // per buffer: K tile [64 kv][128 d] at [0,8192), V tile [128 d][64 t] at [8192,16384)
  __shared__ alignas(16) unsigned short lds[2][16384];   // 64 KB
  __shared__ alignas(16) unsigned short plds[8][1024];   // 16 KB, per-wave P [16 q][64 kv]
  const int t = threadIdx.x;
  const int wid = t >> 6, lane = t & 63;
  const int llo = lane & 15, lhi = lane >> 4;
  const int j0 = blockIdx.x;
  int bh, g;
  if (j0 < 256) { bh = j0 & 31; g = 15 - (j0 >> 5); }
  else          { bh = (j0 - 256) & 31; g = (j0 - 256) >> 5; }
  const int qbase = g * 128;
  const int nt = 2 * g + 2;
  const size_t bh_td = (size_t)bh * SEQ * HD;
  const size_t bh_dt = (size_t)bh * HD * SEQ;
  unsigned short* pw = &plds[wid][0];
  const int fvl = (llo & 7) ^ ((llo & 8) >> 1);  // V read swizzle key (rows d=db*16+llo)
  const int pkey = llo & 14;                      // P slot swizzle key (even -> aligned b128)

  auto stage = [&](int buf, int j) {
    const int t0 = j * 64;
    #pragma unroll
    for (int i = 0; i < 2; ++i) {       // K: 1024 chunks of 16B
      const int c = i * 512 + t;
      const int row = c >> 4, slot = c & 15;
      gload_lds16(Kt + bh_td + (size_t)(t0 + row) * HD + ((slot ^ (row & 15)) << 3),
                  &lds[buf][(size_t)(i * 512 + wid * 64) * 8]);
    }
    #pragma unroll
    for (int i = 0; i < 2; ++i) {       // V: 1024 chunks of 16B
      const int c = i * 512 + t;
      const int vrow = c >> 3, vslot = c & 7;
      const int fv = (vrow & 7) ^ ((vrow & 8) >> 1);
      gload_lds16(VT + bh_dt + (size_t)vrow * SEQ + t0 + ((vslot ^ fv) << 3),
                  &lds[buf][8192 + (size_t)(i * 512 + wid * 64) * 8]);
    }
  };

  // Q fragments: wave wid owns q rows qbase + wid*16 + [0,16); B-operand (n = q = llo)
  bf16x8 qa[4];
  {
    const unsigned short* qp = Q + bh_td + (size_t)(qbase + wid * 16 + llo) * HD + lhi * 8;
    #pragma unroll
    for (int kk = 0; kk < 4; ++kk) qa[kk] = *(const bf16x8*)(qp + kk * 32);
  }
  f32x4 oacc[8] = {};
  float m_r = -1e30f, l_r = 0.f;   // per-lane state for q = qbase + wid*16 + llo

  stage(0, 0);
  for (int j = 0; j < nt; ++j) {
    const int cur = j & 1;
    __syncthreads();                    // staged lds[cur] ready; prior reads of lds[cur] done
    if (j + 1 < nt) stage(cur ^ 1, j + 1);
    // ---- QK^T (swapped: A=K, B=Q) -> s[nb][r] = S[kv=j*64+nb*16+lhi*4+r][q=llo] ----
    f32x4 s[4] = {};
    __builtin_amdgcn_s_setprio(1);
    #pragma unroll
    for (int nb = 0; nb < 4; ++nb) {
      const int row = nb * 16 + llo;
      #pragma unroll
      for (int kk = 0; kk < 4; ++kk) {
        const bf16x8 kb = *(const bf16x8*)&lds[cur][row * 128 + (((kk * 4 + lhi) ^ llo) << 3)];
        s[nb] = __builtin_amdgcn_mfma_f32_16x16x32_bf16(kb, qa[kk], s[nb], 0, 0, 0);
      }
    }
    __builtin_amdgcn_s_setprio(0);
    // ---- causal mask (only last two tiles touch the diagonal band) ----
    if (j >= nt - 2) {
      const int q = qbase + wid * 16 + llo;
      #pragma unroll
      for (int nb = 0; nb < 4; ++nb)
        #pragma unroll
        for (int r = 0; r < 4; ++r)
          if (j * 64 + nb * 16 + lhi * 4 + r > q) s[nb][r] = -1e30f;
    }
    // ---- online softmax: in-lane max of 16, then 2 cross-lhi shuffles ----
    float mloc = -1e30f;
    #pragma unroll
    for (int nb = 0; nb < 4; ++nb)
      #pragma unroll
      for (int r = 0; r < 4; ++r) mloc = fmaxf(mloc, s[nb][r]);
    mloc = fmaxf(mloc, __shfl_xor(mloc, 16));
    mloc = fmaxf(mloc, __shfl_xor(mloc, 32));
    float alq = 1.f;
    if (__any(mloc > m_r + 8.f)) {      // defer-max: rescale only on real growth
      const float mn = fmaxf(m_r, mloc);
      alq = __expf(m_r - mn);
      m_r = mn;
      float alr[4];
      #pragma unroll
      for (int r = 0; r < 4; ++r) alr[r] = __shfl(alq, lhi * 4 + r);
      #pragma unroll
      for (int db = 0; db < 8; ++db)
        #pragma unroll
        for (int r = 0; r < 4; ++r) oacc[db][r] *= alr[r];
    }
    // ---- exp, pack pairs, 4x ds_write_b64 (swizzled slots) ----
    float ps = 0.f;
    #pragma unroll
    for (int nb = 0; nb < 4; ++nb) {
      const float p0 = __expf(s[nb][0] - m_r), p1 = __expf(s[nb][1] - m_r);
      const float p2 = __expf(s[nb][2] - m_r), p3 = __expf(s[nb][3] - m_r);
      ps += (p0 + p1) + (p2 + p3);
      uint2 uu;
      uu.x = (uint32_t)f2bf(p0) | ((uint32_t)f2bf(p1) << 16);
      uu.y = (uint32_t)f2bf(p2) | ((uint32_t)f2bf(p3) << 16);
      *(uint2*)&pw[llo * 64 + (((nb * 4 + lhi) ^ pkey) << 2)] = uu;
    }
    ps += __shfl_xor(ps, 16);
    ps += __shfl_xor(ps, 32);
    l_r = l_r * alq + ps;
    asm volatile("s_waitcnt lgkmcnt(0)" ::: "memory");
    __builtin_amdgcn_sched_barrier(0);
    // ---- P A-fragments: lane reads P[q=llo][kv = c*32 + lhi*8 .. +7] ----
    const bf16x8 pa0 = *(const bf16x8*)&pw[llo * 64 + (((lhi * 2) ^ pkey) << 2)];
    const bf16x8 pa1 = *(const bf16x8*)&pw[llo * 64 + (((8 + lhi * 2) ^ pkey) << 2)];
    // ---- PV (V from LDS, staged+swizzled) ----
    __builtin_amdgcn_s_setprio(1);
    #pragma unroll
    for (int db = 0; db < 8; ++db) {
      const unsigned short* vbp = &lds[cur][8192 + (db * 16 + llo) * 64];
      const bf16x8 vb0 = *(const bf16x8*)&vbp[(lhi ^ fvl) << 3];
      const bf16x8 vb1 = *(const bf16x8*)&vbp[((4 + lhi) ^ fvl) << 3];
      oacc[db] = __builtin_amdgcn_mfma_f32_16x16x32_bf16(pa0, vb0, oacc[db], 0, 0, 0);
      oacc[db] = __builtin_amdgcn_mfma_f32_16x16x32_bf16(pa1, vb1, oacc[db], 0, 0, 0);
    }
    __builtin_amdgcn_s_setprio(0);
  }

  // ---- epilogue: O rows q = lhi*4+r need 1/l from lane llo = lhi*4+r ----
  const int b = bh >> 4, h = bh & 15;
  const float invq = 1.f / l_r;
  float invr[4];
  #pragma unroll
  for (int r = 0; r < 4; ++r) invr[r] = __shfl(invq, lhi * 4 + r);
  #pragma unroll
  for (int db = 0; db < 8; ++db)
    #pragma unroll
    for (int r = 0; r < 4; ++r) {
      const int qi = qbase + wid * 16 + lhi * 4 + r;
      const int d = db * 16 + llo;
      O[((size_t)(b * SEQ + qi)) * D_MODEL + h * HD + d] = f2bf(oacc[db][r] * invr[r]);
    }
}

extern "C" void kernel_launch(void* const* d_in, const int* in_sizes, int n_in,
                              void* d_out, int out_size, void* d_ws, size_t ws_size,
                              hipStream_t stream) {
  const float* x  = (const float*)d_in[0];
  const float* wq = (const float*)d_in[1];
  const float* wk = (const float*)d_in[2];
  const float* wv = (const float*)d_in[3];
  const float* wo = (const float*)d_in[4];

  char* ws = (char*)d_ws;
  float* scales   = (float*)ws;                     // 4 f32
  float* partials = (float*)(ws + 256);             // 4*4096 f32 = 64 KB
  unsigned short* xbf   = (unsigned short*)(ws + 131072);
  const size_t nMD = (size_t)M_TOT * D_MODEL;
  unsigned short* signs = xbf + nMD;
  unsigned short* Qb = signs + 4 * (size_t)NELEM_W;
  unsigned short* Kb = Qb + nMD;
  unsigned short* Vt = Kb + nMD;
  unsigned short* Ab = Vt + nMD;

  sign_w<<<dim3(4096, 4), 256, 0, stream>>>(wq, wk, wv, wo, signs, partials);
  reduce2<<<dim3(4), 256, 0, stream>>>(partials, scales);
  cvt_x<<<dim3(8192), 256, 0, stream>>>(x, xbf);

  gemm_bt<0><<<dim3(16, 32), 256, 0, stream>>>(xbf, signs,                       (void*)Qb, scales, 0, 0.08838834764831845f);
  gemm_bt<0><<<dim3(16, 32), 256, 0, stream>>>(xbf, signs + (size_t)NELEM_W,     (void*)Kb, scales, 1, 1.0f);
  gemm_bt<1><<<dim3(16, 32), 256, 0, stream>>>(xbf, signs + 2 * (size_t)NELEM_W, (void*)Vt, scales, 2, 1.0f);

  attn_fwd<<<dim3(512), 512, 0, stream>>>(Qb, Kb, Vt, Ab);

  gemm_bt<2><<<dim3(16, 32), 256, 0, stream>>>(Ab, signs + 3 * (size_t)NELEM_W, d_out, scales, 3, 1.0f);
}